// Round 7
// baseline (467.976 us; speedup 1.0000x reference)
//
#include <hip/hip_runtime.h>
#include <math.h>

// Problem constants (from reference)
#define BATCH 1024
#define DIM   512            // K; also fp8 row bytes
#define NCLS  100000
#define SCALE_S 64.0f
#define MARGIN  0.5f
#define EPS_REF 1e-7f
#define SEXP 92.332482616893656878f   // S * log2(e): acc = S*log2e*wf -> exp2(acc)

// Fused-GEMM tiling
#define NSLAB 64             // classes (N) per block; W slab lives in LDS (fragment order)
#define NBLK  1563           // ceil(NCLS/NSLAB)
#define CHUNK 16             // batch rows per compute chunk
#define NCHUNK_WAVE 16       // chunks per wave: 1024 rows / (16 rows * 4 waves)
#define NRSCOPY 8            // rowsum replicas (atomic line-contention /8, XCD-aligned)

typedef __attribute__((ext_vector_type(4))) float floatx4;
typedef __attribute__((ext_vector_type(2))) long  longx2;

#if __has_builtin(__builtin_amdgcn_exp2f)
#define EXP2(x) __builtin_amdgcn_exp2f(x)
#else
#define EXP2(x) exp2f(x)
#endif

// sum within each 16-lane group
__device__ __forceinline__ float red16(float v) {
    v += __shfl_xor(v, 1);
    v += __shfl_xor(v, 2);
    v += __shfl_xor(v, 4);
    v += __shfl_xor(v, 8);
    return v;
}

// ---------- prep: per-row ||x||, exact tgt logit, xf8 in MFMA-fragment order ----------
// xf8 row layout: byte k stored at quad(k)*128 + kk(k)*8 + (k&7), quad=(k&31)>>3,
// kk=k>>5. Lane (quad,l15) reads its full-K A-fragment set as 128 contiguous
// bytes at row*512 + quad*128; 8B word at +kk*8 is the A-operand for MFMA step kk.
__global__ __launch_bounds__(256)
void k_prep(const float* __restrict__ features,
            const float* __restrict__ W,
            const int* __restrict__ y,
            unsigned char* __restrict__ xf8,
            float* __restrict__ rowsum,
            float* __restrict__ tgt) {
    const int row = blockIdx.x;
    const int t = threadIdx.x;
    const int lane = t & 63;
    const int wave = t >> 6;
    __shared__ float redS[4], redD[4];

    const float2 v  = *(const float2*)(features + (size_t)row * DIM + t * 2);
    const float2 wv = *(const float2*)(W + (size_t)y[row] * DIM + t * 2);
    float ss = v.x * v.x + v.y * v.y;
    float dd = v.x * wv.x + v.y * wv.y;
    #pragma unroll
    for (int m = 32; m >= 1; m >>= 1) { ss += __shfl_xor(ss, m); dd += __shfl_xor(dd, m); }
    if (lane == 0) { redS[wave] = ss; redD[wave] = dd; }
    __syncthreads();
    const float tot  = redS[0] + redS[1] + redS[2] + redS[3];
    const float dtot = redD[0] + redD[1] + redD[2] + redD[3];
    const float nrm = fmaxf(sqrtf(tot), 1e-12f);
    const float sc = SEXP / nrm;

    int pk = __builtin_amdgcn_cvt_pk_fp8_f32(v.x * sc, v.y * sc, 0, false);
    const int k0 = t * 2;                       // k0,k0+1 adjacent in frag order
    const int off = ((k0 & 31) >> 3) * 128 + (k0 >> 5) * 8 + (k0 & 7);
    *(unsigned short*)(xf8 + (size_t)row * DIM + off) = (unsigned short)(pk & 0xFFFF);

    if (t < NRSCOPY) rowsum[t * BATCH + row] = 0.0f;
    if (t == 0) tgt[row] = dtot / nrm;
}

// ---------- fused W-convert + streamed-B fp8 MFMA + exp2-sum ----------
// Round-6 lesson: the allocator refuses 128 persistent B-VGPRs (VGPR pinned at
// 100 across 3 formulations; it spills/refetches B per use). So design FOR
// streamed B: Ws is stored in MFMA-fragment order (row r byte k at
// r*512 + quad*128 + kk*8 + (k&7)), 16B chunks XOR-swizzled by (jj^(r&7)).
// One ds_read_b128 = two kk-steps of one strip -> 32 b128/chunk feed 64 MFMAs,
// 4 independent acc chains, only 16 transient B regs in flight.

// per-jj step: 4 strip b128 loads + 8 MFMAs (all literal indices)
#define STEPJ(Ab, jj) {                                                        \
    const longx2 q0 = *(const longx2*)(&Ws[0 * 8192 + bbase + (((jj) ^ swb) << 4)]); \
    const longx2 q1 = *(const longx2*)(&Ws[1 * 8192 + bbase + (((jj) ^ swb) << 4)]); \
    const longx2 q2 = *(const longx2*)(&Ws[2 * 8192 + bbase + (((jj) ^ swb) << 4)]); \
    const longx2 q3 = *(const longx2*)(&Ws[3 * 8192 + bbase + (((jj) ^ swb) << 4)]); \
    const long a0 = Ab[jj][0];                                                 \
    const long a1 = Ab[jj][1];                                                 \
    acc0 = __builtin_amdgcn_mfma_f32_16x16x32_fp8_fp8(a0, q0[0], acc0, 0, 0, 0); \
    acc1 = __builtin_amdgcn_mfma_f32_16x16x32_fp8_fp8(a0, q1[0], acc1, 0, 0, 0); \
    acc2 = __builtin_amdgcn_mfma_f32_16x16x32_fp8_fp8(a0, q2[0], acc2, 0, 0, 0); \
    acc3 = __builtin_amdgcn_mfma_f32_16x16x32_fp8_fp8(a0, q3[0], acc3, 0, 0, 0); \
    acc0 = __builtin_amdgcn_mfma_f32_16x16x32_fp8_fp8(a1, q0[1], acc0, 0, 0, 0); \
    acc1 = __builtin_amdgcn_mfma_f32_16x16x32_fp8_fp8(a1, q1[1], acc1, 0, 0, 0); \
    acc2 = __builtin_amdgcn_mfma_f32_16x16x32_fp8_fp8(a1, q2[1], acc2, 0, 0, 0); \
    acc3 = __builtin_amdgcn_mfma_f32_16x16x32_fp8_fp8(a1, q3[1], acc3, 0, 0, 0); }

#define LA(Ab, c) { const unsigned char* p_ = abase + (size_t)(c) * (CHUNK * DIM); \
    Ab[0] = *(const longx2*)(p_ +  0); Ab[1] = *(const longx2*)(p_ + 16);      \
    Ab[2] = *(const longx2*)(p_ + 32); Ab[3] = *(const longx2*)(p_ + 48);      \
    Ab[4] = *(const longx2*)(p_ + 64); Ab[5] = *(const longx2*)(p_ + 80);      \
    Ab[6] = *(const longx2*)(p_ + 96); Ab[7] = *(const longx2*)(p_ + 112); }

#define EPI(reg) { float p_;                                                   \
    if (full) { p_ = EXP2(acc0[reg]) + EXP2(acc1[reg])                         \
                   + EXP2(acc2[reg]) + EXP2(acc3[reg]); }                      \
    else { p_ = 0.f;                                                           \
        if (n0 +      l15 < NCLS) p_ += EXP2(acc0[reg]);                       \
        if (n0 + 16 + l15 < NCLS) p_ += EXP2(acc1[reg]);                       \
        if (n0 + 32 + l15 < NCLS) p_ += EXP2(acc2[reg]);                       \
        if (n0 + 48 + l15 < NCLS) p_ += EXP2(acc3[reg]); }                     \
    p_ = red16(p_);                                                            \
    if (l15 == 0) atomicAdd(&rs[rowb_ + (reg)], p_); }

#define COMPUTE(Ab, c) {                                                       \
    floatx4 acc0 = (floatx4){0.f,0.f,0.f,0.f};                                 \
    floatx4 acc1 = (floatx4){0.f,0.f,0.f,0.f};                                 \
    floatx4 acc2 = (floatx4){0.f,0.f,0.f,0.f};                                 \
    floatx4 acc3 = (floatx4){0.f,0.f,0.f,0.f};                                 \
    STEPJ(Ab,0) STEPJ(Ab,1) STEPJ(Ab,2) STEPJ(Ab,3)                            \
    STEPJ(Ab,4) STEPJ(Ab,5) STEPJ(Ab,6) STEPJ(Ab,7)                            \
    const int rowb_ = (wave * NCHUNK_WAVE + (c)) * CHUNK + quad * 4;           \
    EPI(0) EPI(1) EPI(2) EPI(3) }

__global__ __launch_bounds__(256, 3)
void k_gemm_fused(const float* __restrict__ W,
                  const unsigned char* __restrict__ xf8,
                  float* __restrict__ rowsum) {
    __shared__ __align__(16) unsigned char Ws[NSLAB * DIM];     // 32 KB

    const int tid  = threadIdx.x;
    const int wave = tid >> 6;
    const int lane = tid & 63;
    const int quad = lane >> 4;
    const int l15  = lane & 15;
    const int n0   = blockIdx.x * NSLAB;
    float* rs = rowsum + (blockIdx.x & (NRSCOPY - 1)) * BATCH;

    // B-read geometry: strip ni row r = ni*16+l15; fragment pair jj at byte
    // ni*8192 + l15*512 + quad*128 + ((jj ^ (l15&7))<<4)
    const int bbase = l15 * 512 + quad * 128;
    const int swb   = l15 & 7;

    // A chunk base for this lane (fragment-order xf8)
    const unsigned char* abase =
        xf8 + (size_t)(wave * NCHUNK_WAVE * CHUNK + l15) * DIM + quad * 128;

    // prefetch chunk 0 while Phase 1 streams W
    longx2 A0[8], A1[8];
    LA(A0, 0)

    // ---- Phase 1: W fp32 -> fp8 e4m3 (RNE) into LDS in FRAGMENT ORDER.
    // Thread handles (r, qd, jj): global floats [jj*64+qd*8, +8) (kk=2jj) and
    // [+32, +8) (kk=2jj+1) -> 16 fp8 bytes -> one 16B store at swizzled chunk.
    #pragma unroll
    for (int j = 0; j < 8; ++j) {
        const int c   = j * 256 + tid;
        const int r   = c >> 5;          // 0..63
        const int rem = c & 31;
        const int jj  = rem >> 2;        // 0..7 (kk pair)
        const int qd  = rem & 3;         // 0..3 (quad)
        int rg = n0 + r; if (rg > NCLS - 1) rg = NCLS - 1;   // tail clamp (masked later)
        const float* src = W + (size_t)rg * DIM + jj * 64 + qd * 8;
        const float4 e0 = *(const float4*)(src);
        const float4 e1 = *(const float4*)(src + 4);
        const float4 o0 = *(const float4*)(src + 32);
        const float4 o1 = *(const float4*)(src + 36);
        int w0 = __builtin_amdgcn_cvt_pk_fp8_f32(e0.x, e0.y, 0, false);
        w0     = __builtin_amdgcn_cvt_pk_fp8_f32(e0.z, e0.w, w0, true);
        int w1 = __builtin_amdgcn_cvt_pk_fp8_f32(e1.x, e1.y, 0, false);
        w1     = __builtin_amdgcn_cvt_pk_fp8_f32(e1.z, e1.w, w1, true);
        int w2 = __builtin_amdgcn_cvt_pk_fp8_f32(o0.x, o0.y, 0, false);
        w2     = __builtin_amdgcn_cvt_pk_fp8_f32(o0.z, o0.w, w2, true);
        int w3 = __builtin_amdgcn_cvt_pk_fp8_f32(o1.x, o1.y, 0, false);
        w3     = __builtin_amdgcn_cvt_pk_fp8_f32(o1.z, o1.w, w3, true);
        *(int4*)(&Ws[r * 512 + ((qd * 8 + (jj ^ (r & 7))) << 4)]) =
            make_int4(w0, w1, w2, w3);
    }
    __syncthreads();

    const bool full = (n0 + NSLAB <= NCLS);

    // ---- Phase 2: chunk loop; A dbuf from global (L2-hot), B streamed from
    // LDS via b128 (2 kk-steps per read). No barriers in the hot loop.
    #pragma unroll 1
    for (int c = 0; c < NCHUNK_WAVE; c += 2) {
        LA(A1, c + 1)
        COMPUTE(A0, c)
        const int cn = (c + 2 < NCHUNK_WAVE) ? c + 2 : 0;   // last prefetch harmless
        LA(A0, cn)
        COMPUTE(A1, c + 1)
    }
}

// ---------- finalize loss ----------
__global__ void k_finalize(const float* __restrict__ rowsum,
                           const float* __restrict__ tgt,
                           float* __restrict__ out) {
    const int tid = threadIdx.x;
    const int lane = tid & 63;
    const int wave = tid >> 6;
    __shared__ float red[4];

    float s = 0.f;
    #pragma unroll
    for (int i = 0; i < 4; ++i) {
        const int b = tid + i * 256;
        float rsum = 0.f;
        #pragma unroll
        for (int cp = 0; cp < NRSCOPY; ++cp) rsum += rowsum[cp * BATCH + b];
        const float traw = tgt[b];
        const float tc = fminf(fmaxf(traw, -1.0f + EPS_REF), 1.0f - EPS_REF);
        const float num = SCALE_S * cosf(acosf(tc) + MARGIN);
        const float excl = rsum - expf(SCALE_S * traw);
        const float denom = expf(num) + excl;
        s += num - logf(denom);
    }
    #pragma unroll
    for (int m = 32; m >= 1; m >>= 1) s += __shfl_xor(s, m);
    if (lane == 0) red[wave] = s;
    __syncthreads();
    if (tid == 0)
        out[0] = -(red[0] + red[1] + red[2] + red[3]) / (float)BATCH;
}

extern "C" void kernel_launch(void* const* d_in, const int* in_sizes, int n_in,
                              void* d_out, int out_size, void* d_ws, size_t ws_size,
                              hipStream_t stream) {
    const float* features = (const float*)d_in[0];
    const float* W        = (const float*)d_in[1];
    const int*   y        = (const int*)d_in[2];
    float* out = (float*)d_out;

    const size_t XF8_BYTES = (size_t)BATCH * DIM;      // 524,288
    const size_t RS_BYTES  = (size_t)NRSCOPY * BATCH * sizeof(float);   // 32 KB
    char* ws = (char*)d_ws;
    unsigned char* xf8 = (unsigned char*)ws;
    float* rowsum = (float*)(ws + XF8_BYTES);
    float* tgt    = (float*)(ws + XF8_BYTES + RS_BYTES);

    k_prep<<<BATCH, 256, 0, stream>>>(features, W, y, xf8, rowsum, tgt);
    k_gemm_fused<<<NBLK, 256, 0, stream>>>(W, xf8, rowsum);
    k_finalize<<<1, 256, 0, stream>>>(rowsum, tgt, out);
}

// Round 8
// 380.689 us; speedup vs baseline: 1.2293x; 1.2293x over previous
//
#include <hip/hip_runtime.h>
#include <math.h>

// Problem constants (from reference)
#define BATCH 1024
#define DIM   512            // K; also fp8 row bytes
#define NCLS  100000
#define SCALE_S 64.0f
#define MARGIN  0.5f
#define EPS_REF 1e-7f
#define SEXP 92.332482616893656878f   // S * log2(e): acc = S*log2e*wf -> exp2(acc)

// Fused-GEMM tiling
#define NSLAB 64             // classes (N) per block; W slab lives in LDS (fragment order)
#define NBLK  1563           // ceil(NCLS/NSLAB)
#define CHUNK 16             // batch rows per compute chunk
#define NCHUNK_WAVE 16       // chunks per wave: 1024 rows / (16 rows * 4 waves)
#define NRSCOPY 8            // rowsum replicas (atomic line-contention /8, XCD-aligned)

typedef __attribute__((ext_vector_type(4))) float floatx4;
typedef __attribute__((ext_vector_type(2))) long  longx2;

#if __has_builtin(__builtin_amdgcn_exp2f)
#define EXP2(x) __builtin_amdgcn_exp2f(x)
#else
#define EXP2(x) exp2f(x)
#endif

// sum within each 16-lane group — pure VALU via DPP (keeps the DS pipe free
// for B-streaming; ~8cy latency/step vs ~60+ for shfl). Steps: row_ror:8,
// row_ror:4 (within 16-lane row), quad_perm xor2, quad_perm xor1.
__device__ __forceinline__ float red16(float v) {
    int x;
    x = __builtin_amdgcn_update_dpp(0, __builtin_bit_cast(int, v), 0x128, 0xf, 0xf, true);
    v += __builtin_bit_cast(float, x);
    x = __builtin_amdgcn_update_dpp(0, __builtin_bit_cast(int, v), 0x124, 0xf, 0xf, true);
    v += __builtin_bit_cast(float, x);
    x = __builtin_amdgcn_update_dpp(0, __builtin_bit_cast(int, v), 0x4E, 0xf, 0xf, true);
    v += __builtin_bit_cast(float, x);
    x = __builtin_amdgcn_update_dpp(0, __builtin_bit_cast(int, v), 0xB1, 0xf, 0xf, true);
    v += __builtin_bit_cast(float, x);
    return v;
}

// ---------- prep: per-row ||x||, exact tgt logit, xf8 in MFMA-fragment order ----------
// xf8 row layout: byte k stored at quad(k)*128 + kk(k)*8 + (k&7), quad=(k&31)>>3,
// kk=k>>5. Lane (quad,l15) reads its full-K A-fragment set as 128 contiguous
// bytes at row*512 + quad*128; 8B word at +kk*8 is the A-operand for MFMA step kk.
__global__ __launch_bounds__(256)
void k_prep(const float* __restrict__ features,
            const float* __restrict__ W,
            const int* __restrict__ y,
            unsigned char* __restrict__ xf8,
            float* __restrict__ rowsum,
            float* __restrict__ tgt) {
    const int row = blockIdx.x;
    const int t = threadIdx.x;
    const int lane = t & 63;
    const int wave = t >> 6;
    __shared__ float redS[4], redD[4];

    const float2 v  = *(const float2*)(features + (size_t)row * DIM + t * 2);
    const float2 wv = *(const float2*)(W + (size_t)y[row] * DIM + t * 2);
    float ss = v.x * v.x + v.y * v.y;
    float dd = v.x * wv.x + v.y * wv.y;
    #pragma unroll
    for (int m = 32; m >= 1; m >>= 1) { ss += __shfl_xor(ss, m); dd += __shfl_xor(dd, m); }
    if (lane == 0) { redS[wave] = ss; redD[wave] = dd; }
    __syncthreads();
    const float tot  = redS[0] + redS[1] + redS[2] + redS[3];
    const float dtot = redD[0] + redD[1] + redD[2] + redD[3];
    const float nrm = fmaxf(sqrtf(tot), 1e-12f);
    const float sc = SEXP / nrm;

    int pk = __builtin_amdgcn_cvt_pk_fp8_f32(v.x * sc, v.y * sc, 0, false);
    const int k0 = t * 2;                       // k0,k0+1 adjacent in frag order
    const int off = ((k0 & 31) >> 3) * 128 + (k0 >> 5) * 8 + (k0 & 7);
    *(unsigned short*)(xf8 + (size_t)row * DIM + off) = (unsigned short)(pk & 0xFFFF);

    if (t < NRSCOPY) rowsum[t * BATCH + row] = 0.0f;
    if (t == 0) tgt[row] = dtot / nrm;
}

// ---------- fused W-convert + streamed-B fp8 MFMA + exp2-sum ----------
// R6/R7 lessons combined: (1) allocator refuses 128 persistent B-VGPRs -> B is
// streamed from LDS; (2) fragment-order b128 B-layout measured conflict-clean
// (0.37 extra cy/read) and halves DS ops vs b64; (3) launch_bounds(256,3)
// caused scratch spills (+35MB FETCH/WRITE, VGPR 84) -> keep (256,2);
// (4) epilogue reduce moved off the DS pipe (DPP); (5) setprio around MFMAs
// (waves are independent here — the regime where T5 measured +4-7%).

// per-jj step: 4 strip b128 loads + 8 MFMAs (all literal indices)
#define STEPJ(Ab, jj) {                                                        \
    const longx2 q0 = *(const longx2*)(&Ws[0 * 8192 + bbase + (((jj) ^ swb) << 4)]); \
    const longx2 q1 = *(const longx2*)(&Ws[1 * 8192 + bbase + (((jj) ^ swb) << 4)]); \
    const longx2 q2 = *(const longx2*)(&Ws[2 * 8192 + bbase + (((jj) ^ swb) << 4)]); \
    const longx2 q3 = *(const longx2*)(&Ws[3 * 8192 + bbase + (((jj) ^ swb) << 4)]); \
    const long a0 = Ab[jj][0];                                                 \
    const long a1 = Ab[jj][1];                                                 \
    acc0 = __builtin_amdgcn_mfma_f32_16x16x32_fp8_fp8(a0, q0[0], acc0, 0, 0, 0); \
    acc1 = __builtin_amdgcn_mfma_f32_16x16x32_fp8_fp8(a0, q1[0], acc1, 0, 0, 0); \
    acc2 = __builtin_amdgcn_mfma_f32_16x16x32_fp8_fp8(a0, q2[0], acc2, 0, 0, 0); \
    acc3 = __builtin_amdgcn_mfma_f32_16x16x32_fp8_fp8(a0, q3[0], acc3, 0, 0, 0); \
    acc0 = __builtin_amdgcn_mfma_f32_16x16x32_fp8_fp8(a1, q0[1], acc0, 0, 0, 0); \
    acc1 = __builtin_amdgcn_mfma_f32_16x16x32_fp8_fp8(a1, q1[1], acc1, 0, 0, 0); \
    acc2 = __builtin_amdgcn_mfma_f32_16x16x32_fp8_fp8(a1, q2[1], acc2, 0, 0, 0); \
    acc3 = __builtin_amdgcn_mfma_f32_16x16x32_fp8_fp8(a1, q3[1], acc3, 0, 0, 0); }

#define LA(Ab, c) { const unsigned char* p_ = abase + (size_t)(c) * (CHUNK * DIM); \
    Ab[0] = *(const longx2*)(p_ +  0); Ab[1] = *(const longx2*)(p_ + 16);      \
    Ab[2] = *(const longx2*)(p_ + 32); Ab[3] = *(const longx2*)(p_ + 48);      \
    Ab[4] = *(const longx2*)(p_ + 64); Ab[5] = *(const longx2*)(p_ + 80);      \
    Ab[6] = *(const longx2*)(p_ + 96); Ab[7] = *(const longx2*)(p_ + 112); }

#define EPI(reg) { float p_;                                                   \
    if (full) { p_ = EXP2(acc0[reg]) + EXP2(acc1[reg])                         \
                   + EXP2(acc2[reg]) + EXP2(acc3[reg]); }                      \
    else { p_ = 0.f;                                                           \
        if (n0 +      l15 < NCLS) p_ += EXP2(acc0[reg]);                       \
        if (n0 + 16 + l15 < NCLS) p_ += EXP2(acc1[reg]);                       \
        if (n0 + 32 + l15 < NCLS) p_ += EXP2(acc2[reg]);                       \
        if (n0 + 48 + l15 < NCLS) p_ += EXP2(acc3[reg]); }                     \
    p_ = red16(p_);                                                            \
    if (l15 == 0) atomicAdd(&rs[rowb_ + (reg)], p_); }

#define COMPUTE(Ab, c) {                                                       \
    floatx4 acc0 = (floatx4){0.f,0.f,0.f,0.f};                                 \
    floatx4 acc1 = (floatx4){0.f,0.f,0.f,0.f};                                 \
    floatx4 acc2 = (floatx4){0.f,0.f,0.f,0.f};                                 \
    floatx4 acc3 = (floatx4){0.f,0.f,0.f,0.f};                                 \
    __builtin_amdgcn_s_setprio(1);                                             \
    STEPJ(Ab,0) STEPJ(Ab,1) STEPJ(Ab,2) STEPJ(Ab,3)                            \
    STEPJ(Ab,4) STEPJ(Ab,5) STEPJ(Ab,6) STEPJ(Ab,7)                            \
    __builtin_amdgcn_s_setprio(0);                                             \
    const int rowb_ = (wave * NCHUNK_WAVE + (c)) * CHUNK + quad * 4;           \
    EPI(0) EPI(1) EPI(2) EPI(3) }

__global__ __launch_bounds__(256, 2)
void k_gemm_fused(const float* __restrict__ W,
                  const unsigned char* __restrict__ xf8,
                  float* __restrict__ rowsum) {
    __shared__ __align__(16) unsigned char Ws[NSLAB * DIM];     // 32 KB

    const int tid  = threadIdx.x;
    const int wave = tid >> 6;
    const int lane = tid & 63;
    const int quad = lane >> 4;
    const int l15  = lane & 15;
    const int n0   = blockIdx.x * NSLAB;
    float* rs = rowsum + (blockIdx.x & (NRSCOPY - 1)) * BATCH;

    // B-read geometry: strip ni row r = ni*16+l15; fragment pair jj at byte
    // ni*8192 + l15*512 + quad*128 + ((jj ^ (l15&7))<<4)
    const int bbase = l15 * 512 + quad * 128;
    const int swb   = l15 & 7;

    // A chunk base for this lane (fragment-order xf8)
    const unsigned char* abase =
        xf8 + (size_t)(wave * NCHUNK_WAVE * CHUNK + l15) * DIM + quad * 128;

    // prefetch chunk 0 while Phase 1 streams W
    longx2 A0[8], A1[8];
    LA(A0, 0)

    // ---- Phase 1: W fp32 -> fp8 e4m3 (RNE) into LDS in FRAGMENT ORDER.
    // Thread handles (r, qd, jj): global floats [jj*64+qd*8, +8) (kk=2jj) and
    // [+32, +8) (kk=2jj+1) -> 16 fp8 bytes -> one 16B store at swizzled chunk.
    #pragma unroll
    for (int j = 0; j < 8; ++j) {
        const int c   = j * 256 + tid;
        const int r   = c >> 5;          // 0..63
        const int rem = c & 31;
        const int jj  = rem >> 2;        // 0..7 (kk pair)
        const int qd  = rem & 3;         // 0..3 (quad)
        int rg = n0 + r; if (rg > NCLS - 1) rg = NCLS - 1;   // tail clamp (masked later)
        const float* src = W + (size_t)rg * DIM + jj * 64 + qd * 8;
        const float4 e0 = *(const float4*)(src);
        const float4 e1 = *(const float4*)(src + 4);
        const float4 o0 = *(const float4*)(src + 32);
        const float4 o1 = *(const float4*)(src + 36);
        int w0 = __builtin_amdgcn_cvt_pk_fp8_f32(e0.x, e0.y, 0, false);
        w0     = __builtin_amdgcn_cvt_pk_fp8_f32(e0.z, e0.w, w0, true);
        int w1 = __builtin_amdgcn_cvt_pk_fp8_f32(e1.x, e1.y, 0, false);
        w1     = __builtin_amdgcn_cvt_pk_fp8_f32(e1.z, e1.w, w1, true);
        int w2 = __builtin_amdgcn_cvt_pk_fp8_f32(o0.x, o0.y, 0, false);
        w2     = __builtin_amdgcn_cvt_pk_fp8_f32(o0.z, o0.w, w2, true);
        int w3 = __builtin_amdgcn_cvt_pk_fp8_f32(o1.x, o1.y, 0, false);
        w3     = __builtin_amdgcn_cvt_pk_fp8_f32(o1.z, o1.w, w3, true);
        *(int4*)(&Ws[r * 512 + ((qd * 8 + (jj ^ (r & 7))) << 4)]) =
            make_int4(w0, w1, w2, w3);
    }
    __syncthreads();

    const bool full = (n0 + NSLAB <= NCLS);

    // ---- Phase 2: chunk loop; A dbuf from global (L2-hot), B streamed from
    // LDS via b128 (2 kk-steps per read). No barriers in the hot loop.
    #pragma unroll 1
    for (int c = 0; c < NCHUNK_WAVE; c += 2) {
        LA(A1, c + 1)
        COMPUTE(A0, c)
        const int cn = (c + 2 < NCHUNK_WAVE) ? c + 2 : 0;   // last prefetch harmless
        LA(A0, cn)
        COMPUTE(A1, c + 1)
    }
}

// ---------- finalize loss ----------
__global__ void k_finalize(const float* __restrict__ rowsum,
                           const float* __restrict__ tgt,
                           float* __restrict__ out) {
    const int tid = threadIdx.x;
    const int lane = tid & 63;
    const int wave = tid >> 6;
    __shared__ float red[4];

    float s = 0.f;
    #pragma unroll
    for (int i = 0; i < 4; ++i) {
        const int b = tid + i * 256;
        float rsum = 0.f;
        #pragma unroll
        for (int cp = 0; cp < NRSCOPY; ++cp) rsum += rowsum[cp * BATCH + b];
        const float traw = tgt[b];
        const float tc = fminf(fmaxf(traw, -1.0f + EPS_REF), 1.0f - EPS_REF);
        const float num = SCALE_S * cosf(acosf(tc) + MARGIN);
        const float excl = rsum - expf(SCALE_S * traw);
        const float denom = expf(num) + excl;
        s += num - logf(denom);
    }
    #pragma unroll
    for (int m = 32; m >= 1; m >>= 1) s += __shfl_xor(s, m);
    if (lane == 0) red[wave] = s;
    __syncthreads();
    if (tid == 0)
        out[0] = -(red[0] + red[1] + red[2] + red[3]) / (float)BATCH;
}

extern "C" void kernel_launch(void* const* d_in, const int* in_sizes, int n_in,
                              void* d_out, int out_size, void* d_ws, size_t ws_size,
                              hipStream_t stream) {
    const float* features = (const float*)d_in[0];
    const float* W        = (const float*)d_in[1];
    const int*   y        = (const int*)d_in[2];
    float* out = (float*)d_out;

    const size_t XF8_BYTES = (size_t)BATCH * DIM;      // 524,288
    const size_t RS_BYTES  = (size_t)NRSCOPY * BATCH * sizeof(float);   // 32 KB
    char* ws = (char*)d_ws;
    unsigned char* xf8 = (unsigned char*)ws;
    float* rowsum = (float*)(ws + XF8_BYTES);
    float* tgt    = (float*)(ws + XF8_BYTES + RS_BYTES);

    k_prep<<<BATCH, 256, 0, stream>>>(features, W, y, xf8, rowsum, tgt);
    k_gemm_fused<<<NBLK, 256, 0, stream>>>(W, xf8, rowsum);
    k_finalize<<<1, 256, 0, stream>>>(rowsum, tgt, out);
}